// Round 1
// baseline (556.379 us; speedup 1.0000x reference)
//
#include <hip/hip_runtime.h>

// ---------------------------------------------------------------------------
// Fused 3x3 valid conv (64->128) + bias + *2 + min over output channels.
// Implicit-GEMM via mfma_f32_16x16x32_bf16.
//   Block: 512 threads (8 waves), output tile 32(W) x 16(H) = 512 pixels,
//   all 128 oc. Wave tile: 4 M-tiles x 8 N-tiles (128 acc VGPRs).
//   K = 576 = 2 ic-chunks x 9 taps x 32 ic; each tap is one K=32 mfma step.
// LDS: x tile [18 rows][34 cols][32 ic pad 40] = 48,960 B  (pad 40: stride
//      80 B = 20 banks -> 2-way-free b128 frag reads, 16-B aligned)
//      W tile [128 oc][9*32 pad 296]           = 75,776 B  (stride 592 B)
//      total 124,736 B -> 1 block/CU, 2 waves/SIMD.
// ---------------------------------------------------------------------------

#define TW 32
#define TH 16
#define ICP 40
#define XROWS 18
#define XCOLS 34
#define WPAD 296
#define XTILE_ELEMS (XROWS * XCOLS * ICP)          // 24480
#define WTILE_ELEMS (128 * WPAD)                   // 37888
#define LDS_BYTES ((XTILE_ELEMS + WTILE_ELEMS) * 2) // 124736

typedef __attribute__((ext_vector_type(8))) short short8;
typedef __attribute__((ext_vector_type(4))) float f32x4;

__device__ __forceinline__ unsigned short f2bf(float f) {
  unsigned int u = __builtin_bit_cast(unsigned int, f);
  u += 0x7FFFu + ((u >> 16) & 1u);   // round-to-nearest-even
  return (unsigned short)(u >> 16);
}

// W fp32 [oc=128][ic=64][kh=3][kw=3] -> ws bf16 [chunk=2][oc=128][tap=9][ic=32]
__global__ void repack_w_kernel(const float* __restrict__ w,
                                unsigned short* __restrict__ wb) {
  int e = blockIdx.x * 256 + threadIdx.x;
  if (e >= 2 * 128 * 9 * 32) return;
  int ic_in = e & 31;
  int tap   = (e >> 5) % 9;
  int oc    = (e / 288) & 127;
  int c     = e / 36864;
  int ic    = c * 32 + ic_in;
  wb[e] = f2bf(w[(oc * 64 + ic) * 9 + tap]);
}

__global__ __launch_bounds__(512, 2) void conv_min_kernel(
    const float* __restrict__ x, const unsigned short* __restrict__ wb,
    const float* __restrict__ bias, float* __restrict__ out) {
  extern __shared__ unsigned short lds[];
  unsigned short* xs = lds;                  // [row][col][icp]
  unsigned short* wl = lds + XTILE_ELEMS;    // [oc][WPAD]

  const int tid  = threadIdx.x;
  const int wv   = tid >> 6;
  const int lane = tid & 63;
  const int q    = lane >> 4;
  const int cl   = lane & 15;

  const int W0 = blockIdx.x * TW;
  const int H0 = blockIdx.y * TH;
  const int b  = blockIdx.z;

  f32x4 acc[4][8];
#pragma unroll
  for (int j = 0; j < 4; ++j)
#pragma unroll
    for (int n = 0; n < 8; ++n)
      acc[j][n] = (f32x4){0.0f, 0.0f, 0.0f, 0.0f};

  const float* xb = x + (size_t)b * 64 * 65536;

  for (int c = 0; c < 2; ++c) {
    if (c) __syncthreads();  // previous phase's LDS reads must finish

    // ---- stage x ic-chunk: 18*34 pixels x 16 ic-pairs, fp32->bf16 ----
    for (int i = tid; i < XROWS * XCOLS * 16; i += 512) {
      int pair = i / (XROWS * XCOLS);
      int rc   = i - pair * (XROWS * XCOLS);
      int row  = rc / XCOLS;
      int col  = rc - row * XCOLS;
      int ic   = c * 32 + pair * 2;
      int gr   = min(H0 + row, 255);  // clamp: clamped data only feeds
      int gc   = min(W0 + col, 255);  // pixels that are never stored
      const float* xp = xb + (size_t)ic * 65536 + gr * 256 + gc;
      unsigned int pk = (unsigned int)f2bf(xp[0]) |
                        ((unsigned int)f2bf(xp[65536]) << 16);
      *(unsigned int*)&xs[(row * XCOLS + col) * ICP + pair * 2] = pk;
    }

    // ---- stage W chunk (already bf16 in ws): 36864 elems as uint4 ----
    {
      const unsigned short* wsrc = wb + c * 36864;
      for (int i = tid; i < 4608; i += 512) {
        int oc = i / 36;
        int r8 = (i - oc * 36) * 8;
        uint4 v = *(const uint4*)(wsrc + oc * 288 + r8);
        *(uint4*)&wl[oc * WPAD + r8] = v;
      }
    }
    __syncthreads();

    // ---- compute: 9 taps, each one K=32 mfma step over 32 ic ----
#pragma unroll
    for (int tap = 0; tap < 9; ++tap) {
      const int kh = tap / 3, kw = tap % 3;
      short8 af[4];
#pragma unroll
      for (int j = 0; j < 4; ++j) {
        int t  = wv * 4 + j;
        int hr = (t >> 1) + kh;
        int cc = (t & 1) * 16 + cl + kw;
        af[j] = *(const short8*)&xs[(hr * XCOLS + cc) * ICP + q * 8];
      }
      short8 bfr[8];
#pragma unroll
      for (int n = 0; n < 8; ++n) {
        int oc = n * 16 + cl;
        bfr[n] = *(const short8*)&wl[oc * WPAD + tap * 32 + q * 8];
      }
#pragma unroll
      for (int j = 0; j < 4; ++j)
#pragma unroll
        for (int n = 0; n < 8; ++n)
          acc[j][n] = __builtin_amdgcn_mfma_f32_16x16x32_bf16(
              af[j], bfr[n], acc[j][n], 0, 0, 0);
    }
  }

  // ---- epilogue: (acc + bias)*2, min over 128 oc, store ----
  float bv[8];
#pragma unroll
  for (int n = 0; n < 8; ++n) bv[n] = bias[n * 16 + cl];

#pragma unroll
  for (int j = 0; j < 4; ++j) {
    int t   = wv * 4 + j;
    int oh  = H0 + (t >> 1);
    int owb = W0 + (t & 1) * 16;
    float mn[4] = {INFINITY, INFINITY, INFINITY, INFINITY};
#pragma unroll
    for (int n = 0; n < 8; ++n)
#pragma unroll
      for (int r = 0; r < 4; ++r)
        mn[r] = fminf(mn[r], (acc[j][n][r] + bv[n]) * 2.0f);
#pragma unroll
    for (int r = 0; r < 4; ++r) {
      mn[r] = fminf(mn[r], __shfl_xor(mn[r], 1));
      mn[r] = fminf(mn[r], __shfl_xor(mn[r], 2));
      mn[r] = fminf(mn[r], __shfl_xor(mn[r], 4));
      mn[r] = fminf(mn[r], __shfl_xor(mn[r], 8));
      int m  = q * 4 + r;       // C/D: row = quad*4 + reg, col = lane&15
      int ow = owb + m;
      if (cl == m && oh < 254 && ow < 254)
        out[((size_t)b * 254 + oh) * 254 + ow] = mn[r];
    }
  }
}

extern "C" void kernel_launch(void* const* d_in, const int* in_sizes, int n_in,
                              void* d_out, int out_size, void* d_ws,
                              size_t ws_size, hipStream_t stream) {
  const float* x    = (const float*)d_in[0];
  const float* w    = (const float*)d_in[1];
  const float* bias = (const float*)d_in[2];
  float* out        = (float*)d_out;
  unsigned short* wb = (unsigned short*)d_ws;  // 147,456 B bf16 weights

  hipFuncSetAttribute(reinterpret_cast<const void*>(conv_min_kernel),
                      hipFuncAttributeMaxDynamicSharedMemorySize, LDS_BYTES);

  // ws is re-poisoned before every call -> repack every call (same work).
  repack_w_kernel<<<288, 256, 0, stream>>>(w, wb);

  dim3 grid(8, 16, 16);  // ceil(254/32), ceil(254/16), batch
  conv_min_kernel<<<grid, 512, LDS_BYTES, stream>>>(x, wb, bias, out);
}